// Round 2
// baseline (1015.095 us; speedup 1.0000x reference)
//
#include <hip/hip_runtime.h>
#include <math.h>

#define N_IN_F 28
#define N_HID 16
#define N_OUT 2
#define SCAN_CHUNK 512

// ---------------- CSR build ----------------

__global__ void k_zero(int* __restrict__ deg, int n) {
    int i = blockIdx.x * blockDim.x + threadIdx.x;
    if (i < n) deg[i] = 0;
}

__global__ void k_hist(const int* __restrict__ dst, int* __restrict__ deg, int ne) {
    int e = blockIdx.x * blockDim.x + threadIdx.x;
    if (e < ne) atomicAdd(&deg[dst[e]], 1);
}

__global__ void k_scan_partial(const int* __restrict__ deg, int* __restrict__ partial, int n) {
    __shared__ int sm[SCAN_CHUNK];
    int i = blockIdx.x * SCAN_CHUNK + threadIdx.x;
    sm[threadIdx.x] = (i < n) ? deg[i] : 0;
    __syncthreads();
    for (int off = SCAN_CHUNK / 2; off > 0; off >>= 1) {
        if (threadIdx.x < off) sm[threadIdx.x] += sm[threadIdx.x + off];
        __syncthreads();
    }
    if (threadIdx.x == 0) partial[blockIdx.x] = sm[0];
}

// single block of 1024: exclusive scan of partial[nchunks], nchunks <= 1024
__global__ void k_scan_top(int* __restrict__ partial, int nchunks) {
    __shared__ int sm[1024];
    int v = (threadIdx.x < nchunks) ? partial[threadIdx.x] : 0;
    sm[threadIdx.x] = v;
    __syncthreads();
    for (int off = 1; off < 1024; off <<= 1) {
        int t = (threadIdx.x >= off) ? sm[threadIdx.x - off] : 0;
        __syncthreads();
        sm[threadIdx.x] += t;
        __syncthreads();
    }
    if (threadIdx.x < nchunks) partial[threadIdx.x] = sm[threadIdx.x] - v;  // exclusive
}

__global__ void k_scan_write(const int* __restrict__ deg, const int* __restrict__ partial,
                             int* __restrict__ row_start, int* __restrict__ cursor,
                             int n, int ne) {
    __shared__ int sm[SCAN_CHUNK];
    int i = blockIdx.x * SCAN_CHUNK + threadIdx.x;
    int v = (i < n) ? deg[i] : 0;
    sm[threadIdx.x] = v;
    __syncthreads();
    for (int off = 1; off < SCAN_CHUNK; off <<= 1) {
        int t = (threadIdx.x >= off) ? sm[threadIdx.x - off] : 0;
        __syncthreads();
        sm[threadIdx.x] += t;
        __syncthreads();
    }
    if (i < n) {
        int excl = sm[threadIdx.x] - v + partial[blockIdx.x];
        row_start[i] = excl;
        cursor[i] = excl;
    }
    if (i == n - 1) row_start[n] = ne;
}

__global__ void k_scatter(const int* __restrict__ src, const int* __restrict__ dst,
                          int* __restrict__ cursor, int* __restrict__ csr_src, int ne) {
    int e = blockIdx.x * blockDim.x + threadIdx.x;
    if (e >= ne) return;
    int d = dst[e];
    int pos = atomicAdd(&cursor[d], 1);
    csr_src[pos] = src[e];
}

// ---------------- GCN compute ----------------

// per-node: dis = rsqrt(deg+1); hs1 = (x @ W1) * dis
__global__ void k_h1(const float* __restrict__ x, const float* __restrict__ W1,
                     const int* __restrict__ deg, float* __restrict__ dis,
                     float* __restrict__ hs1, int n) {
    __shared__ float w[N_IN_F * N_HID];
    for (int t = threadIdx.x; t < N_IN_F * N_HID; t += blockDim.x) w[t] = W1[t];
    __syncthreads();
    int i = blockIdx.x * blockDim.x + threadIdx.x;
    if (i >= n) return;

    float xi[N_IN_F];
    const float* xr = x + (size_t)i * N_IN_F;
#pragma unroll
    for (int k = 0; k < N_IN_F; ++k) xi[k] = xr[k];

    float di = rsqrtf((float)(deg[i] + 1));  // +1 self-loop
    dis[i] = di;

    float* hs = hs1 + (size_t)i * N_HID;
#pragma unroll
    for (int f = 0; f < N_HID; ++f) {
        float h = 0.0f;
#pragma unroll
        for (int k = 0; k < N_IN_F; ++k) h = fmaf(xi[k], w[k * N_HID + f], h);
        hs[f] = h * di;
    }
}

// 16 lanes per node (one per feature): gather-sum hs1 over CSR neighbors,
// then fused: v = relu(dis*acc + b1); h2 = v @ W2 (cross-lane reduce); hs2 = h2*dis
__global__ void __launch_bounds__(256)
k_agg1(const int* __restrict__ row_start, const int* __restrict__ csr_src,
       const float* __restrict__ hs1, const float* __restrict__ dis,
       const float* __restrict__ b1, const float* __restrict__ W2,
       float2* __restrict__ hs2, int n) {
    int t = blockIdx.x * blockDim.x + threadIdx.x;
    int node = t >> 4;
    int f = t & 15;
    if (node >= n) return;

    int beg = row_start[node];
    int end = row_start[node + 1];
    float acc = hs1[(size_t)node * N_HID + f];  // self-loop seed
    float a0 = 0.f, a1 = 0.f, a2 = 0.f, a3 = 0.f;
    int j = beg;
    for (; j + 4 <= end; j += 4) {
        int s0 = csr_src[j];
        int s1 = csr_src[j + 1];
        int s2 = csr_src[j + 2];
        int s3 = csr_src[j + 3];
        a0 += hs1[(size_t)s0 * N_HID + f];
        a1 += hs1[(size_t)s1 * N_HID + f];
        a2 += hs1[(size_t)s2 * N_HID + f];
        a3 += hs1[(size_t)s3 * N_HID + f];
    }
    for (; j < end; ++j) acc += hs1[(size_t)csr_src[j] * N_HID + f];
    acc += (a0 + a1) + (a2 + a3);

    float di = dis[node];
    float v = fmaxf(fmaf(di, acc, b1[f]), 0.0f);
    float c0 = v * W2[2 * f + 0];
    float c1 = v * W2[2 * f + 1];
#pragma unroll
    for (int off = 8; off > 0; off >>= 1) {
        c0 += __shfl_xor(c0, off, 16);
        c1 += __shfl_xor(c1, off, 16);
    }
    if (f == 0) {
        float2 o;
        o.x = c0 * di;
        o.y = c1 * di;
        hs2[node] = o;
    }
}

// 4 lanes per node: gather-sum hs2 (float2) over CSR neighbors, fused log_softmax
__global__ void __launch_bounds__(256)
k_agg2(const int* __restrict__ row_start, const int* __restrict__ csr_src,
       const float2* __restrict__ hs2, const float* __restrict__ dis,
       const float* __restrict__ b2, float* __restrict__ out, int n) {
    int t = blockIdx.x * blockDim.x + threadIdx.x;
    int node = t >> 2;
    int l = t & 3;
    if (node >= n) return;

    int beg = row_start[node];
    int end = row_start[node + 1];
    float cx = 0.f, cy = 0.f;
    for (int j = beg + l; j < end; j += 4) {
        float2 v = hs2[csr_src[j]];
        cx += v.x;
        cy += v.y;
    }
#pragma unroll
    for (int off = 2; off > 0; off >>= 1) {
        cx += __shfl_xor(cx, off, 4);
        cy += __shfl_xor(cy, off, 4);
    }
    if (l == 0) {
        float2 self = hs2[node];
        cx += self.x;
        cy += self.y;
        float di = dis[node];
        float a = fmaf(di, cx, b2[0]);
        float b = fmaf(di, cy, b2[1]);
        float m = fmaxf(a, b);
        float lse = m + logf(expf(a - m) + expf(b - m));
        out[(size_t)node * 2 + 0] = a - lse;
        out[(size_t)node * 2 + 1] = b - lse;
    }
}

// ---------------- launch ----------------

extern "C" void kernel_launch(void* const* d_in, const int* in_sizes, int n_in,
                              void* d_out, int out_size, void* d_ws, size_t ws_size,
                              hipStream_t stream) {
    const float* x  = (const float*)d_in[0];
    const int*   ei = (const int*)d_in[1];
    const float* W1 = (const float*)d_in[2];
    const float* b1 = (const float*)d_in[3];
    const float* W2 = (const float*)d_in[4];
    const float* b2 = (const float*)d_in[5];
    float* out = (float*)d_out;

    const int n  = in_sizes[0] / N_IN_F;   // 200000
    const int ne = in_sizes[1] / 2;        // 6400000
    const int* src = ei;
    const int* dst = ei + ne;

    const int nchunks = (n + SCAN_CHUNK - 1) / SCAN_CHUNK;  // 391 <= 1024

    // workspace layout: ints first (all counts multiples of 4 -> 16B aligned)
    int* ws_i = (int*)d_ws;
    int* deg       = ws_i;                    // n
    int* row_start = deg + n;                 // n+4 (padded)
    int* cursor    = row_start + n + 4;       // n
    int* partial   = cursor + n;              // 1024
    int* csr_src   = partial + 1024;          // ne
    float* dis = (float*)(csr_src + ne);      // n
    float* hs1 = dis + n;                     // n*16
    float2* hs2 = (float2*)(hs1 + (size_t)n * N_HID);  // n (float2)

    const int B = 256;
    dim3 blk(B);

    k_zero<<<dim3((n + B - 1) / B), blk, 0, stream>>>(deg, n);
    k_hist<<<dim3((ne + B - 1) / B), blk, 0, stream>>>(dst, deg, ne);
    k_scan_partial<<<dim3(nchunks), dim3(SCAN_CHUNK), 0, stream>>>(deg, partial, n);
    k_scan_top<<<dim3(1), dim3(1024), 0, stream>>>(partial, nchunks);
    k_scan_write<<<dim3(nchunks), dim3(SCAN_CHUNK), 0, stream>>>(deg, partial, row_start, cursor, n, ne);
    k_scatter<<<dim3((ne + B - 1) / B), blk, 0, stream>>>(src, dst, cursor, csr_src, ne);
    k_h1<<<dim3((n + B - 1) / B), blk, 0, stream>>>(x, W1, deg, dis, hs1, n);
    {
        long long tot = (long long)n * 16;
        k_agg1<<<dim3((unsigned)((tot + B - 1) / B)), blk, 0, stream>>>(
            row_start, csr_src, hs1, dis, b1, W2, hs2, n);
    }
    {
        long long tot = (long long)n * 4;
        k_agg2<<<dim3((unsigned)((tot + B - 1) / B)), blk, 0, stream>>>(
            row_start, csr_src, hs2, dis, b2, out, n);
    }
}